// Round 8
// baseline (380.882 us; speedup 1.0000x reference)
//
#include <hip/hip_runtime.h>

#define N_NODES 1024
#define E_EDGES 524288
#define FE 64
#define FC 128
#define NLAYERS 3

typedef unsigned short u16;
typedef __attribute__((ext_vector_type(8))) short bf16x8;   // MFMA A/B frag
typedef __attribute__((ext_vector_type(4))) float f32x4;    // MFMA C/D frag
typedef __attribute__((ext_vector_type(8))) unsigned short u16x8;
typedef __attribute__((ext_vector_type(4))) unsigned short u16x4;

__device__ __forceinline__ float bf2f(u16 u) {
    return __uint_as_float(((unsigned)u) << 16);
}
__device__ __forceinline__ u16 f2bf(float f) {
    unsigned x = __float_as_uint(f);
    return (u16)((x + 0x7FFFu + ((x >> 16) & 1u)) >> 16);   // RNE
}

// ---------------------------------------------------------------------------
// Setup (1024 blocks, one per node): zero S row, copy node->nodeA, transpose
// W_fij into bf16 Wt (blocks 0..47), and layer-0 projections fni/fnj/h.
// ---------------------------------------------------------------------------
__global__ __launch_bounds__(256) void setup_kernel(
    const float* __restrict__ node_feature, const float* __restrict__ Wfij,
    u16* __restrict__ Wt,
    const float* __restrict__ Wni, const float* __restrict__ Wnj,
    const float* __restrict__ Wnode, const float* __restrict__ bias,
    u16* __restrict__ fni, u16* __restrict__ fnj,
    float* __restrict__ h, float* __restrict__ S, float* __restrict__ nodeA)
{
    __shared__ float row[FC];
    const int d = blockIdx.x;
    const int t = threadIdx.x;

    reinterpret_cast<float4*>(S + (size_t)d * N_NODES)[t] = make_float4(0.f, 0.f, 0.f, 0.f);

    if (t < FC) {
        const float v = node_feature[d * FC + t];
        nodeA[d * FC + t] = v;
        row[t] = v;
    }
    if (d < (NLAYERS * FE * FE) / 256) {
        const int i = d * 256 + t;
        const int l = i >> 12, rem = i & 4095;
        const int n = rem >> 6, k = rem & 63;
        Wt[(size_t)l * 4096 + n * 64 + k] = f2bf(Wfij[(size_t)l * 4096 + k * 64 + n]);
    }
    __syncthreads();

    if (t < 64) {
        float a = 0.f;
        #pragma unroll 8
        for (int k = 0; k < FC; k++) a = fmaf(row[k], Wni[k * FE + t], a);
        fni[d * FE + t] = f2bf(a);
    } else if (t < 128) {
        const int f = t - 64;
        float a = 0.f;
        #pragma unroll 8
        for (int k = 0; k < FC; k++) a = fmaf(row[k], Wnj[k * FE + f], a);
        fnj[d * FE + f] = f2bf(a);
    } else {
        const int c = t - 128;
        float a = bias[c];
        #pragma unroll 8
        for (int k = 0; k < FC; k++) a = fmaf(row[k], Wnode[k * FC + c], a);
        h[d * FC + c] = a;
    }
}

// ---------------------------------------------------------------------------
// MFMA edge kernel, OPERAND-SWAPPED (r8): D = Wt-view[A] x ef-view[B] so
// C col = EDGE, row = n. Each lane owns one edge el = wbase + (lane&15);
// the 4 16-lane groups hold disjoint 16-n slices of the same 16 edges.
// Zero LDS, zero barriers:
//  - fni/fnj gathered per lane as 8B u16x4 at the lane's n-slice
//  - logit reduce = 2 shfl_xor (16, 32)
//  - ef' read-modify-write directly in global at the lane's n-slice
//    (disjoint cols per grp; FIRST recomputes ef0 from x, no ef read)
// Fragment layouts (m89 family):
//   A(row=lane&15 -> n, k=(lane>>4)*8+j) = Wt[n][k]   (same frags as r7)
//   B(col=lane&15 -> e, same k)          = ef[e][k]   (same frags as r7)
//   C(col=lane&15 -> e, row=(lane>>4)*4+r -> n)
// ---------------------------------------------------------------------------
template <bool FIRST, bool WRITE_EF>
__global__ void edge_mfma_kernel(
    u16* __restrict__ ef,                 // [E][64] bf16 (in/out)
    const float* __restrict__ x,          // [E][2]   (FIRST only)
    const float* __restrict__ Win,        // [2][64]  (FIRST only)
    const float* __restrict__ bin,        // [64]     (FIRST only)
    const u16* __restrict__ Wt,           // [64 n][64 k] bf16 (this layer)
    const u16* __restrict__ fni, const u16* __restrict__ fnj,
    const int* __restrict__ src, const int* __restrict__ dst,
    const float* __restrict__ attn,       // [64] fp32
    float* __restrict__ S)                // [N][N] fp32 (pre-zeroed)
{
    const int lane = threadIdx.x & 63;
    const int wid  = threadIdx.x >> 6;
    const int l15  = lane & 15;
    const int grp  = lane >> 4;                       // 0..3 (n-slice)
    const int el   = blockIdx.x * 64 + wid * 16 + l15;   // this lane's edge

    const int se = src[el];
    const int de = dst[el];

    // --- B-operand: ef[el][k], k = half*32 + grp*8 + j ---
    bf16x8 efr0, efr1;
    float2 xx;
    if constexpr (FIRST) {
        xx = *reinterpret_cast<const float2*>(x + 2 * (size_t)el);
        #pragma unroll
        for (int half = 0; half < 2; half++) {
            const int c0 = half * 32 + grp * 8;
            const float4 wA0 = *reinterpret_cast<const float4*>(Win + c0);
            const float4 wA1 = *reinterpret_cast<const float4*>(Win + c0 + 4);
            const float4 wB0 = *reinterpret_cast<const float4*>(Win + FE + c0);
            const float4 wB1 = *reinterpret_cast<const float4*>(Win + FE + c0 + 4);
            const float4 b0  = *reinterpret_cast<const float4*>(bin + c0);
            const float4 b1  = *reinterpret_cast<const float4*>(bin + c0 + 4);
            bf16x8 fr;
            fr[0] = (short)f2bf(fmaf(xx.x, wA0.x, fmaf(xx.y, wB0.x, b0.x)));
            fr[1] = (short)f2bf(fmaf(xx.x, wA0.y, fmaf(xx.y, wB0.y, b0.y)));
            fr[2] = (short)f2bf(fmaf(xx.x, wA0.z, fmaf(xx.y, wB0.z, b0.z)));
            fr[3] = (short)f2bf(fmaf(xx.x, wA0.w, fmaf(xx.y, wB0.w, b0.w)));
            fr[4] = (short)f2bf(fmaf(xx.x, wA1.x, fmaf(xx.y, wB1.x, b1.x)));
            fr[5] = (short)f2bf(fmaf(xx.x, wA1.y, fmaf(xx.y, wB1.y, b1.y)));
            fr[6] = (short)f2bf(fmaf(xx.x, wA1.z, fmaf(xx.y, wB1.z, b1.z)));
            fr[7] = (short)f2bf(fmaf(xx.x, wA1.w, fmaf(xx.y, wB1.w, b1.w)));
            if (half == 0) efr0 = fr; else efr1 = fr;
        }
    } else {
        const size_t arow = (size_t)el * FE;
        efr0 = *reinterpret_cast<const bf16x8*>(ef + arow + grp * 8);
        efr1 = *reinterpret_cast<const bf16x8*>(ef + arow + 32 + grp * 8);
    }

    // --- A-operand: Wt[n][k]; n = nt*16+l15, k = ks*32+grp*8+j ---
    bf16x8 wfr[2][4];
    #pragma unroll
    for (int ks = 0; ks < 2; ks++)
        #pragma unroll
        for (int nt = 0; nt < 4; nt++)
            wfr[ks][nt] = *reinterpret_cast<const bf16x8*>(
                Wt + (size_t)(nt * 16 + l15) * 64 + ks * 32 + grp * 8);

    // --- gathers at this lane's n-slice: cols nt*16 + grp*4 .. +3 ---
    u16x4 gi[4], gj[4];
    f32x4 av[4];
    #pragma unroll
    for (int nt = 0; nt < 4; nt++) {
        const int c0 = nt * 16 + grp * 4;
        gi[nt] = *reinterpret_cast<const u16x4*>(fni + (size_t)se * FE + c0);
        gj[nt] = *reinterpret_cast<const u16x4*>(fnj + (size_t)de * FE + c0);
        av[nt] = *reinterpret_cast<const f32x4*>(attn + c0);
    }

    f32x4 acc[4];
    #pragma unroll
    for (int nt = 0; nt < 4; nt++) {
        acc[nt] = (f32x4){0.f, 0.f, 0.f, 0.f};
        acc[nt] = __builtin_amdgcn_mfma_f32_16x16x32_bf16(wfr[0][nt], efr0, acc[nt], 0, 0, 0);
        acc[nt] = __builtin_amdgcn_mfma_f32_16x16x32_bf16(wfr[1][nt], efr1, acc[nt], 0, 0, 0);
    }

    // --- epilogue: adds + leaky_relu + logit, all in registers ---
    float vv[4][4];
    float logit = 0.f;
    #pragma unroll
    for (int nt = 0; nt < 4; nt++) {
        #pragma unroll
        for (int r = 0; r < 4; r++) {
            float v = acc[nt][r] + bf2f(gi[nt][r]) + bf2f(gj[nt][r]);
            v = v > 0.f ? v : 0.2f * v;
            vv[nt][r] = v;
            logit = fmaf(v, av[nt][r], logit);
        }
    }

    // --- reduce across the 4 n-slice groups (lanes l15, +16, +32, +48) ---
    logit += __shfl_xor(logit, 16, 64);
    logit += __shfl_xor(logit, 32, 64);
    const float pv = expf(logit);
    if (grp == 0) {
        atomicAdd(S + (size_t)de * N_NODES + se, pv);
    }

    // --- ef write-back at the lane's n-slice (disjoint across grp) ---
    if constexpr (WRITE_EF) {
        #pragma unroll
        for (int nt = 0; nt < 4; nt++) {
            const int c0 = nt * 16 + grp * 4;
            u16* gp = ef + (size_t)el * FE + c0;
            f32x4 oldv;
            if constexpr (FIRST) {
                const float4 w0 = *reinterpret_cast<const float4*>(Win + c0);
                const float4 w1 = *reinterpret_cast<const float4*>(Win + FE + c0);
                const float4 bb = *reinterpret_cast<const float4*>(bin + c0);
                oldv[0] = fmaf(xx.x, w0.x, fmaf(xx.y, w1.x, bb.x));
                oldv[1] = fmaf(xx.x, w0.y, fmaf(xx.y, w1.y, bb.y));
                oldv[2] = fmaf(xx.x, w0.z, fmaf(xx.y, w1.z, bb.z));
                oldv[3] = fmaf(xx.x, w0.w, fmaf(xx.y, w1.w, bb.w));
            } else {
                const u16x4 ov = *reinterpret_cast<const u16x4*>(gp);
                oldv[0] = bf2f(ov[0]); oldv[1] = bf2f(ov[1]);
                oldv[2] = bf2f(ov[2]); oldv[3] = bf2f(ov[3]);
            }
            u16x4 o;
            #pragma unroll
            for (int r = 0; r < 4; r++) o[r] = f2bf(oldv[r] + vv[nt][r]);
            *reinterpret_cast<u16x4*>(gp) = o;
        }
    }
}

// ---------------------------------------------------------------------------
// spmm (+fusions): nout = nin + (S@h)/rowsum(S).  For !LAST additionally:
// re-zero S row, write nodeA, next-layer projections (h double-buffered).
// ---------------------------------------------------------------------------
template <bool LAST>
__global__ __launch_bounds__(256) void spmm_kernel(
    float* __restrict__ S, const float* __restrict__ h,
    const float* __restrict__ nin, float* __restrict__ nout,
    const float* __restrict__ Wni, const float* __restrict__ Wnj,
    const float* __restrict__ Wnode, const float* __restrict__ bias,
    u16* __restrict__ fni, u16* __restrict__ fnj, float* __restrict__ hnext)
{
    __shared__ float red[256];
    __shared__ float rs[2];
    __shared__ float row[FC];
    const int d = blockIdx.x;
    const int t = threadIdx.x;
    const int c = t & 127;
    const int half = t >> 7;
    const float* Srow = S + (size_t)d * N_NODES + half * 512;
    const float* hp = h + (size_t)half * 512 * FC;
    float acc = 0.f, rsum = 0.f;
    #pragma unroll 8
    for (int n = 0; n < 512; n++) {
        const float s = Srow[n];
        rsum += s;
        acc = fmaf(s, hp[n * FC + c], acc);
    }
    red[t] = acc;
    if (c == 0) rs[half] = rsum;
    __syncthreads();

    if constexpr (!LAST) {   // re-zero S row for next layer (reads done)
        reinterpret_cast<float4*>(S + (size_t)d * N_NODES)[t] = make_float4(0.f, 0.f, 0.f, 0.f);
    }
    if (half == 0) {
        const float v = nin[d * FC + c] + (red[c] + red[128 + c]) / (rs[0] + rs[1]);
        nout[d * FC + c] = v;
        if constexpr (!LAST) row[c] = v;
    }

    if constexpr (!LAST) {
        __syncthreads();
        if (t < 64) {
            float a = 0.f;
            #pragma unroll 8
            for (int k = 0; k < FC; k++) a = fmaf(row[k], Wni[k * FE + t], a);
            fni[d * FE + t] = f2bf(a);
        } else if (t < 128) {
            const int f = t - 64;
            float a = 0.f;
            #pragma unroll 8
            for (int k = 0; k < FC; k++) a = fmaf(row[k], Wnj[k * FE + f], a);
            fnj[d * FE + f] = f2bf(a);
        } else {
            const int cc = t - 128;
            float a = bias[cc];
            #pragma unroll 8
            for (int k = 0; k < FC; k++) a = fmaf(row[k], Wnode[k * FC + cc], a);
            hnext[d * FC + cc] = a;
        }
    }
}

// ---------------------------------------------------------------------------
extern "C" void kernel_launch(void* const* d_in, const int* in_sizes, int n_in,
                              void* d_out, int out_size, void* d_ws, size_t ws_size,
                              hipStream_t stream)
{
    const float* node_feature = (const float*)d_in[0];
    const float* edge_feature = (const float*)d_in[1];
    const int*   src          = (const int*)d_in[2];
    const int*   dst          = (const int*)d_in[3];
    const float* W_in         = (const float*)d_in[4];
    const float* b_in         = (const float*)d_in[5];
    const float* W_ni         = (const float*)d_in[6];
    const float* W_nj         = (const float*)d_in[7];
    const float* W_fij        = (const float*)d_in[8];
    const float* W_node       = (const float*)d_in[9];
    const float* attn         = (const float*)d_in[10];
    const float* bias_node    = (const float*)d_in[11];
    float* out = (float*)d_out;

    char* ws = (char*)d_ws;
    size_t off = 0;
    auto alloc = [&](size_t bytes) -> void* {
        void* pp = ws + off;
        off += (bytes + 255) & ~(size_t)255;
        return pp;
    };
    u16*   ef    = (u16*)alloc((size_t)E_EDGES * FE * sizeof(u16));       // 67 MB
    u16*   fni   = (u16*)alloc(N_NODES * FE * sizeof(u16));
    u16*   fnj   = (u16*)alloc(N_NODES * FE * sizeof(u16));
    float* h0    = (float*)alloc(N_NODES * FC * sizeof(float));
    float* h1    = (float*)alloc(N_NODES * FC * sizeof(float));
    float* S     = (float*)alloc((size_t)N_NODES * N_NODES * sizeof(float)); // 4 MB
    float* nodeA = (float*)alloc(N_NODES * FC * sizeof(float));
    u16*   Wt    = (u16*)alloc((size_t)NLAYERS * FE * FE * sizeof(u16));  // 24 KB
    float* hbuf[2] = {h0, h1};

    setup_kernel<<<N_NODES, 256, 0, stream>>>(
        node_feature, W_fij, Wt, W_ni, W_nj, W_node, bias_node,
        fni, fnj, h0, S, nodeA);

    for (int l = 0; l < NLAYERS; l++) {
        float* hl = hbuf[l & 1];
        float* hn = hbuf[(l + 1) & 1];

        if (l == 0) {
            edge_mfma_kernel<true, true><<<E_EDGES / 64, 256, 0, stream>>>(
                ef, edge_feature, W_in, b_in, Wt + (size_t)l * FE * FE,
                fni, fnj, src, dst, attn + (size_t)l * FE, S);
        } else if (l == NLAYERS - 1) {
            edge_mfma_kernel<false, false><<<E_EDGES / 64, 256, 0, stream>>>(
                ef, nullptr, nullptr, nullptr, Wt + (size_t)l * FE * FE,
                fni, fnj, src, dst, attn + (size_t)l * FE, S);
        } else {
            edge_mfma_kernel<false, true><<<E_EDGES / 64, 256, 0, stream>>>(
                ef, nullptr, nullptr, nullptr, Wt + (size_t)l * FE * FE,
                fni, fnj, src, dst, attn + (size_t)l * FE, S);
        }

        if (l == NLAYERS - 1) {
            spmm_kernel<true><<<N_NODES, 256, 0, stream>>>(
                S, hl, nodeA, out,
                nullptr, nullptr, nullptr, nullptr, nullptr, nullptr, nullptr);
        } else {
            const int ln = l + 1;
            spmm_kernel<false><<<N_NODES, 256, 0, stream>>>(
                S, hl, nodeA, nodeA,
                W_ni + (size_t)ln * FC * FE, W_nj + (size_t)ln * FC * FE,
                W_node + (size_t)ln * FC * FC, bias_node + (size_t)ln * FC,
                fni, fnj, hn);
        }
    }
}

// Round 9
// 283.934 us; speedup vs baseline: 1.3414x; 1.3414x over previous
//
#include <hip/hip_runtime.h>

#define N_NODES 1024
#define E_EDGES 524288
#define FE 64
#define FC 128
#define NLAYERS 3

typedef unsigned short u16;
typedef __attribute__((ext_vector_type(8))) short bf16x8;   // MFMA A/B frag
typedef __attribute__((ext_vector_type(4))) float f32x4;    // MFMA C/D frag
typedef __attribute__((ext_vector_type(8))) unsigned short u16x8;

__device__ __forceinline__ float bf2f(u16 u) {
    return __uint_as_float(((unsigned)u) << 16);
}
__device__ __forceinline__ u16 f2bf(float f) {
    unsigned x = __float_as_uint(f);
    return (u16)((x + 0x7FFFu + ((x >> 16) & 1u)) >> 16);   // RNE
}

// ---------------------------------------------------------------------------
// Setup (1024 blocks, one per node): zero S row, copy node->nodeA, transpose
// W_fij into bf16 Wt (blocks 0..47), and layer-0 projections fni/fnj/h.
// ---------------------------------------------------------------------------
__global__ __launch_bounds__(256) void setup_kernel(
    const float* __restrict__ node_feature, const float* __restrict__ Wfij,
    u16* __restrict__ Wt,
    const float* __restrict__ Wni, const float* __restrict__ Wnj,
    const float* __restrict__ Wnode, const float* __restrict__ bias,
    u16* __restrict__ fni, u16* __restrict__ fnj,
    float* __restrict__ h, float* __restrict__ S, float* __restrict__ nodeA)
{
    __shared__ float row[FC];
    const int d = blockIdx.x;
    const int t = threadIdx.x;

    reinterpret_cast<float4*>(S + (size_t)d * N_NODES)[t] = make_float4(0.f, 0.f, 0.f, 0.f);

    if (t < FC) {
        const float v = node_feature[d * FC + t];
        nodeA[d * FC + t] = v;
        row[t] = v;
    }
    if (d < (NLAYERS * FE * FE) / 256) {
        const int i = d * 256 + t;
        const int l = i >> 12, rem = i & 4095;
        const int n = rem >> 6, k = rem & 63;
        Wt[(size_t)l * 4096 + n * 64 + k] = f2bf(Wfij[(size_t)l * 4096 + k * 64 + n]);
    }
    __syncthreads();

    if (t < 64) {
        float a = 0.f;
        #pragma unroll 8
        for (int k = 0; k < FC; k++) a = fmaf(row[k], Wni[k * FE + t], a);
        fni[d * FE + t] = f2bf(a);
    } else if (t < 128) {
        const int f = t - 64;
        float a = 0.f;
        #pragma unroll 8
        for (int k = 0; k < FC; k++) a = fmaf(row[k], Wnj[k * FE + f], a);
        fnj[d * FE + f] = f2bf(a);
    } else {
        const int c = t - 128;
        float a = bias[c];
        #pragma unroll 8
        for (int k = 0; k < FC; k++) a = fmaf(row[k], Wnode[k * FC + c], a);
        h[d * FC + c] = a;
    }
}

// ---------------------------------------------------------------------------
// MFMA edge kernel (r7 structure; r8's zero-LDS swap regressed — per-lane
// 8B gathers + global ef re-read were worse than LDS ops. Keep gathers
// row-coalesced and transposes in LDS.)
// Wave = 16 edges, block = 4 waves (grid E/64), no loop, no block barriers.
// r9 change: stage holds fni[src]+fnj[dst] PRE-SUMMED (fp32 add at staging,
// bf16 store) — halves stage LDS (better occupancy) and halves epilogue
// ds_read_u16 + add count.
//   F    = EF[16x64] @ W[64x64]            (8x mfma_f32_16x16x32_bf16)
//   f    = leaky_relu(F + g, 0.2),  g = staged sum
//   ef' += f   (bf16; via fol LDS transpose + A-frag registers)
//   S[dst][src] += exp(f . attn)           (z == rowsum(S), done in spmm)
// Fragment layouts (m89 family):
//   A: row=lane&15 (edge), k=(lane>>4)*8+j     B: col=lane&15 (n), same k
//   C: col=lane&15 (n),  row=(lane>>4)*4+reg   (edge)
// ---------------------------------------------------------------------------
template <bool FIRST, bool WRITE_EF>
__global__ void edge_mfma_kernel(
    u16* __restrict__ ef,                 // [E][64] bf16 (in/out)
    const float* __restrict__ x,          // [E][2]   (FIRST only)
    const float* __restrict__ Win,        // [2][64]  (FIRST only)
    const float* __restrict__ bin,        // [64]     (FIRST only)
    const u16* __restrict__ Wt,           // [64 n][64 k] bf16 (this layer)
    const u16* __restrict__ fni, const u16* __restrict__ fnj,
    const int* __restrict__ src, const int* __restrict__ dst,
    const float* __restrict__ attn,       // [64] fp32
    float* __restrict__ S)                // [N][N] fp32 (pre-zeroed)
{
    __shared__ __align__(16) u16 stage[4][16][72];               // fni+fnj sum
    __shared__ __align__(16) u16 fol[WRITE_EF ? 4 : 1][16][72];  // f_out rows

    const int lane = threadIdx.x & 63;
    const int wid  = threadIdx.x >> 6;
    const int l15  = lane & 15;
    const int grp  = lane >> 4;                       // 0..3
    const int wbase = blockIdx.x * 64 + wid * 16;

    // --- coalesced gather: stage[row] = bf16(fni[src[e]] + fnj[dst[e]]) ---
    #pragma unroll
    for (int it = 0; it < 2; it++) {
        const int row = it * 8 + (lane >> 3);         // 0..15
        const int e = wbase + row;
        const int c8 = (lane & 7) * 8;
        const u16x8 a = *reinterpret_cast<const u16x8*>(fni + (size_t)src[e] * FE + c8);
        const u16x8 b = *reinterpret_cast<const u16x8*>(fnj + (size_t)dst[e] * FE + c8);
        u16x8 s;
        #pragma unroll
        for (int j = 0; j < 8; j++) s[j] = f2bf(bf2f(a[j]) + bf2f(b[j]));
        *reinterpret_cast<u16x8*>(&stage[wid][row][c8]) = s;
    }

    // --- A fragments: row = wbase+l15, k = half*32 + grp*8 + j ---
    bf16x8 afr0, afr1;
    if constexpr (FIRST) {
        const float2 xx = *reinterpret_cast<const float2*>(x + 2 * (size_t)(wbase + l15));
        #pragma unroll
        for (int half = 0; half < 2; half++) {
            const int c0 = half * 32 + grp * 8;
            const float4 wA0 = *reinterpret_cast<const float4*>(Win + c0);
            const float4 wA1 = *reinterpret_cast<const float4*>(Win + c0 + 4);
            const float4 wB0 = *reinterpret_cast<const float4*>(Win + FE + c0);
            const float4 wB1 = *reinterpret_cast<const float4*>(Win + FE + c0 + 4);
            const float4 b0  = *reinterpret_cast<const float4*>(bin + c0);
            const float4 b1  = *reinterpret_cast<const float4*>(bin + c0 + 4);
            bf16x8 fr;
            fr[0] = (short)f2bf(fmaf(xx.x, wA0.x, fmaf(xx.y, wB0.x, b0.x)));
            fr[1] = (short)f2bf(fmaf(xx.x, wA0.y, fmaf(xx.y, wB0.y, b0.y)));
            fr[2] = (short)f2bf(fmaf(xx.x, wA0.z, fmaf(xx.y, wB0.z, b0.z)));
            fr[3] = (short)f2bf(fmaf(xx.x, wA0.w, fmaf(xx.y, wB0.w, b0.w)));
            fr[4] = (short)f2bf(fmaf(xx.x, wA1.x, fmaf(xx.y, wB1.x, b1.x)));
            fr[5] = (short)f2bf(fmaf(xx.x, wA1.y, fmaf(xx.y, wB1.y, b1.y)));
            fr[6] = (short)f2bf(fmaf(xx.x, wA1.z, fmaf(xx.y, wB1.z, b1.z)));
            fr[7] = (short)f2bf(fmaf(xx.x, wA1.w, fmaf(xx.y, wB1.w, b1.w)));
            if (half == 0) afr0 = fr; else afr1 = fr;
        }
    } else {
        const size_t arow = (size_t)(wbase + l15) * FE;
        afr0 = *reinterpret_cast<const bf16x8*>(ef + arow + grp * 8);
        afr1 = *reinterpret_cast<const bf16x8*>(ef + arow + 32 + grp * 8);
    }

    // --- B fragments: Wt[n][k]; n = nt*16+l15, k = ks*32+grp*8+j ---
    bf16x8 bfr[2][4];
    #pragma unroll
    for (int ks = 0; ks < 2; ks++)
        #pragma unroll
        for (int nt = 0; nt < 4; nt++)
            bfr[ks][nt] = *reinterpret_cast<const bf16x8*>(
                Wt + (size_t)(nt * 16 + l15) * 64 + ks * 32 + grp * 8);

    f32x4 acc[4];
    #pragma unroll
    for (int nt = 0; nt < 4; nt++) {
        acc[nt] = (f32x4){0.f, 0.f, 0.f, 0.f};
        acc[nt] = __builtin_amdgcn_mfma_f32_16x16x32_bf16(afr0, bfr[0][nt], acc[nt], 0, 0, 0);
        acc[nt] = __builtin_amdgcn_mfma_f32_16x16x32_bf16(afr1, bfr[1][nt], acc[nt], 0, 0, 0);
    }

    float an[4];
    #pragma unroll
    for (int nt = 0; nt < 4; nt++) an[nt] = attn[nt * 16 + l15];

    __builtin_amdgcn_wave_barrier();   // stage writes <-> epilogue reads

    // --- epilogue: add staged sum, leaky_relu, logit partials, f_out→LDS ---
    float logit[4] = {0.f, 0.f, 0.f, 0.f};
    #pragma unroll
    for (int nt = 0; nt < 4; nt++) {
        const int n = nt * 16 + l15;
        #pragma unroll
        for (int r = 0; r < 4; r++) {
            const int row = grp * 4 + r;              // edge slot in wave
            float v = acc[nt][r] + bf2f(stage[wid][row][n]);
            v = fmaxf(v, 0.2f * v);                   // leaky_relu(0.2)
            logit[r] = fmaf(v, an[nt], logit[r]);
            if constexpr (WRITE_EF) fol[wid][row][n] = f2bf(v);
        }
    }

    // --- logit reduce (16 lanes/edge) + direct scatter into S ---
    #pragma unroll
    for (int r = 0; r < 4; r++) {
        float t = logit[r];
        t += __shfl_xor(t, 1, 16);
        t += __shfl_xor(t, 2, 16);
        t += __shfl_xor(t, 4, 16);
        t += __shfl_xor(t, 8, 16);
        if (l15 == 0) {
            const int e = wbase + grp * 4 + r;
            atomicAdd(S + (size_t)dst[e] * N_NODES + src[e], expf(t));
        }
    }

    // --- ef write-back from A-frag registers + fol LDS (A layout: row=l15,
    //     cols grp*8.. and 32+grp*8..), 16B stores ---
    if constexpr (WRITE_EF) {
        __builtin_amdgcn_wave_barrier();   // fol writes <-> fol reads
        const u16x8 fo0 = *reinterpret_cast<const u16x8*>(&fol[wid][l15][grp * 8]);
        const u16x8 fo1 = *reinterpret_cast<const u16x8*>(&fol[wid][l15][32 + grp * 8]);
        u16x8 o0, o1;
        #pragma unroll
        for (int j = 0; j < 8; j++) {
            o0[j] = f2bf(bf2f((u16)afr0[j]) + bf2f(fo0[j]));
            o1[j] = f2bf(bf2f((u16)afr1[j]) + bf2f(fo1[j]));
        }
        u16* gp = ef + (size_t)(wbase + l15) * FE;
        *reinterpret_cast<u16x8*>(gp + grp * 8) = o0;
        *reinterpret_cast<u16x8*>(gp + 32 + grp * 8) = o1;
    }
}

// ---------------------------------------------------------------------------
// spmm (+fusions): nout = nin + (S@h)/rowsum(S).  For !LAST additionally:
// re-zero S row, write nodeA, next-layer projections (h double-buffered).
// ---------------------------------------------------------------------------
template <bool LAST>
__global__ __launch_bounds__(256) void spmm_kernel(
    float* __restrict__ S, const float* __restrict__ h,
    const float* __restrict__ nin, float* __restrict__ nout,
    const float* __restrict__ Wni, const float* __restrict__ Wnj,
    const float* __restrict__ Wnode, const float* __restrict__ bias,
    u16* __restrict__ fni, u16* __restrict__ fnj, float* __restrict__ hnext)
{
    __shared__ float red[256];
    __shared__ float rs[2];
    __shared__ float row[FC];
    const int d = blockIdx.x;
    const int t = threadIdx.x;
    const int c = t & 127;
    const int half = t >> 7;
    const float* Srow = S + (size_t)d * N_NODES + half * 512;
    const float* hp = h + (size_t)half * 512 * FC;
    float acc = 0.f, rsum = 0.f;
    #pragma unroll 8
    for (int n = 0; n < 512; n++) {
        const float s = Srow[n];
        rsum += s;
        acc = fmaf(s, hp[n * FC + c], acc);
    }
    red[t] = acc;
    if (c == 0) rs[half] = rsum;
    __syncthreads();

    if constexpr (!LAST) {   // re-zero S row for next layer (reads done)
        reinterpret_cast<float4*>(S + (size_t)d * N_NODES)[t] = make_float4(0.f, 0.f, 0.f, 0.f);
    }
    if (half == 0) {
        const float v = nin[d * FC + c] + (red[c] + red[128 + c]) / (rs[0] + rs[1]);
        nout[d * FC + c] = v;
        if constexpr (!LAST) row[c] = v;
    }

    if constexpr (!LAST) {
        __syncthreads();
        if (t < 64) {
            float a = 0.f;
            #pragma unroll 8
            for (int k = 0; k < FC; k++) a = fmaf(row[k], Wni[k * FE + t], a);
            fni[d * FE + t] = f2bf(a);
        } else if (t < 128) {
            const int f = t - 64;
            float a = 0.f;
            #pragma unroll 8
            for (int k = 0; k < FC; k++) a = fmaf(row[k], Wnj[k * FE + f], a);
            fnj[d * FE + f] = f2bf(a);
        } else {
            const int cc = t - 128;
            float a = bias[cc];
            #pragma unroll 8
            for (int k = 0; k < FC; k++) a = fmaf(row[k], Wnode[k * FC + cc], a);
            hnext[d * FC + cc] = a;
        }
    }
}

// ---------------------------------------------------------------------------
extern "C" void kernel_launch(void* const* d_in, const int* in_sizes, int n_in,
                              void* d_out, int out_size, void* d_ws, size_t ws_size,
                              hipStream_t stream)
{
    const float* node_feature = (const float*)d_in[0];
    const float* edge_feature = (const float*)d_in[1];
    const int*   src          = (const int*)d_in[2];
    const int*   dst          = (const int*)d_in[3];
    const float* W_in         = (const float*)d_in[4];
    const float* b_in         = (const float*)d_in[5];
    const float* W_ni         = (const float*)d_in[6];
    const float* W_nj         = (const float*)d_in[7];
    const float* W_fij        = (const float*)d_in[8];
    const float* W_node       = (const float*)d_in[9];
    const float* attn         = (const float*)d_in[10];
    const float* bias_node    = (const float*)d_in[11];
    float* out = (float*)d_out;

    char* ws = (char*)d_ws;
    size_t off = 0;
    auto alloc = [&](size_t bytes) -> void* {
        void* pp = ws + off;
        off += (bytes + 255) & ~(size_t)255;
        return pp;
    };
    u16*   ef    = (u16*)alloc((size_t)E_EDGES * FE * sizeof(u16));       // 67 MB
    u16*   fni   = (u16*)alloc(N_NODES * FE * sizeof(u16));
    u16*   fnj   = (u16*)alloc(N_NODES * FE * sizeof(u16));
    float* h0    = (float*)alloc(N_NODES * FC * sizeof(float));
    float* h1    = (float*)alloc(N_NODES * FC * sizeof(float));
    float* S     = (float*)alloc((size_t)N_NODES * N_NODES * sizeof(float)); // 4 MB
    float* nodeA = (float*)alloc(N_NODES * FC * sizeof(float));
    u16*   Wt    = (u16*)alloc((size_t)NLAYERS * FE * FE * sizeof(u16));  // 24 KB
    float* hbuf[2] = {h0, h1};

    setup_kernel<<<N_NODES, 256, 0, stream>>>(
        node_feature, W_fij, Wt, W_ni, W_nj, W_node, bias_node,
        fni, fnj, h0, S, nodeA);

    for (int l = 0; l < NLAYERS; l++) {
        float* hl = hbuf[l & 1];
        float* hn = hbuf[(l + 1) & 1];

        if (l == 0) {
            edge_mfma_kernel<true, true><<<E_EDGES / 64, 256, 0, stream>>>(
                ef, edge_feature, W_in, b_in, Wt + (size_t)l * FE * FE,
                fni, fnj, src, dst, attn + (size_t)l * FE, S);
        } else if (l == NLAYERS - 1) {
            edge_mfma_kernel<false, false><<<E_EDGES / 64, 256, 0, stream>>>(
                ef, nullptr, nullptr, nullptr, Wt + (size_t)l * FE * FE,
                fni, fnj, src, dst, attn + (size_t)l * FE, S);
        } else {
            edge_mfma_kernel<false, true><<<E_EDGES / 64, 256, 0, stream>>>(
                ef, nullptr, nullptr, nullptr, Wt + (size_t)l * FE * FE,
                fni, fnj, src, dst, attn + (size_t)l * FE, S);
        }

        if (l == NLAYERS - 1) {
            spmm_kernel<true><<<N_NODES, 256, 0, stream>>>(
                S, hl, nodeA, out,
                nullptr, nullptr, nullptr, nullptr, nullptr, nullptr, nullptr);
        } else {
            const int ln = l + 1;
            spmm_kernel<false><<<N_NODES, 256, 0, stream>>>(
                S, hl, nodeA, nodeA,
                W_ni + (size_t)ln * FC * FE, W_nj + (size_t)ln * FC * FE,
                W_node + (size_t)ln * FC * FC, bias_node + (size_t)ln * FC,
                fni, fnj, hn);
        }
    }
}

// Round 10
// 280.015 us; speedup vs baseline: 1.3602x; 1.0140x over previous
//
#include <hip/hip_runtime.h>

#define N_NODES 1024
#define E_EDGES 524288
#define FE 64
#define FC 128
#define NLAYERS 3

typedef unsigned short u16;
typedef unsigned int u32;
typedef __attribute__((ext_vector_type(8))) short bf16x8;   // MFMA A/B frag
typedef __attribute__((ext_vector_type(4))) float f32x4;    // MFMA C/D frag
typedef __attribute__((ext_vector_type(8))) unsigned short u16x8;
typedef __attribute__((ext_vector_type(4))) unsigned int u32x4;

__device__ __forceinline__ float bf2f(u16 u) {
    return __uint_as_float(((u32)u) << 16);
}
// 2x f32 -> packed bf16 (RNE) in ONE instruction (r10: replaces 5-op integer RNE)
__device__ __forceinline__ u32 cvt2bf(float lo, float hi) {
    u32 r;
    asm("v_cvt_pk_bf16_f32 %0, %1, %2" : "=v"(r) : "v"(lo), "v"(hi));
    return r;
}
__device__ __forceinline__ u16 f2bf(float f) {
    return (u16)cvt2bf(f, 0.f);
}

// ---------------------------------------------------------------------------
// Setup (1024 blocks, one per node): zero S row, copy node->nodeA, transpose
// W_fij into bf16 Wt (blocks 0..47), and layer-0 projections fni/fnj/h.
// ---------------------------------------------------------------------------
__global__ __launch_bounds__(256) void setup_kernel(
    const float* __restrict__ node_feature, const float* __restrict__ Wfij,
    u16* __restrict__ Wt,
    const float* __restrict__ Wni, const float* __restrict__ Wnj,
    const float* __restrict__ Wnode, const float* __restrict__ bias,
    u16* __restrict__ fni, u16* __restrict__ fnj,
    float* __restrict__ h, float* __restrict__ S, float* __restrict__ nodeA)
{
    __shared__ float row[FC];
    const int d = blockIdx.x;
    const int t = threadIdx.x;

    reinterpret_cast<float4*>(S + (size_t)d * N_NODES)[t] = make_float4(0.f, 0.f, 0.f, 0.f);

    if (t < FC) {
        const float v = node_feature[d * FC + t];
        nodeA[d * FC + t] = v;
        row[t] = v;
    }
    if (d < (NLAYERS * FE * FE) / 256) {
        const int i = d * 256 + t;
        const int l = i >> 12, rem = i & 4095;
        const int n = rem >> 6, k = rem & 63;
        Wt[(u32)(l * 4096 + n * 64 + k)] = f2bf(Wfij[(u32)(l * 4096 + k * 64 + n)]);
    }
    __syncthreads();

    if (t < 64) {
        float a0 = 0.f, a1 = 0.f;
        #pragma unroll 8
        for (int k = 0; k < FC; k += 2) {
            a0 = fmaf(row[k],     Wni[k * FE + t], a0);
            a1 = fmaf(row[k + 1], Wni[(k + 1) * FE + t], a1);
        }
        fni[d * FE + t] = f2bf(a0 + a1);
    } else if (t < 128) {
        const int f = t - 64;
        float a0 = 0.f, a1 = 0.f;
        #pragma unroll 8
        for (int k = 0; k < FC; k += 2) {
            a0 = fmaf(row[k],     Wnj[k * FE + f], a0);
            a1 = fmaf(row[k + 1], Wnj[(k + 1) * FE + f], a1);
        }
        fnj[d * FE + f] = f2bf(a0 + a1);
    } else {
        const int c = t - 128;
        float a0 = bias[c], a1 = 0.f;
        #pragma unroll 8
        for (int k = 0; k < FC; k += 2) {
            a0 = fmaf(row[k],     Wnode[k * FC + c], a0);
            a1 = fmaf(row[k + 1], Wnode[(k + 1) * FC + c], a1);
        }
        h[d * FC + c] = a0 + a1;
    }
}

// ---------------------------------------------------------------------------
// MFMA edge kernel (r7/r9 structure; r8's zero-LDS swap regressed — keep
// gathers row-coalesced and transposes in LDS).
// Wave = 16 edges, block = 4 waves (grid E/64), no loop, no block barriers.
// r10: cvt_pk bf16 conversions (1 op vs 5), u32 offsets (no 64-bit addr
// chains), exp2 with log2e-prescaled attn.
//   F    = EF[16x64] @ W[64x64]            (8x mfma_f32_16x16x32_bf16)
//   f    = leaky_relu(F + g, 0.2),  g = staged fni[src]+fnj[dst]
//   ef' += f   (bf16; via fol LDS transpose + A-frag registers)
//   S[dst][src] += exp(f . attn)           (z == rowsum(S), done in spmm)
// Fragment layouts (m89 family):
//   A: row=lane&15 (edge), k=(lane>>4)*8+j     B: col=lane&15 (n), same k
//   C: col=lane&15 (n),  row=(lane>>4)*4+reg   (edge)
// ---------------------------------------------------------------------------
template <bool FIRST, bool WRITE_EF>
__global__ void edge_mfma_kernel(
    u16* __restrict__ ef,                 // [E][64] bf16 (in/out)
    const float* __restrict__ x,          // [E][2]   (FIRST only)
    const float* __restrict__ Win,        // [2][64]  (FIRST only)
    const float* __restrict__ bin,        // [64]     (FIRST only)
    const u16* __restrict__ Wt,           // [64 n][64 k] bf16 (this layer)
    const u16* __restrict__ fni, const u16* __restrict__ fnj,
    const int* __restrict__ src, const int* __restrict__ dst,
    const float* __restrict__ attn,       // [64] fp32
    float* __restrict__ S)                // [N][N] fp32 (pre-zeroed)
{
    __shared__ __align__(16) u16 stage[4][16][72];               // fni+fnj sum
    __shared__ __align__(16) u16 fol[WRITE_EF ? 4 : 1][16][72];  // f_out rows

    const int lane = threadIdx.x & 63;
    const int wid  = threadIdx.x >> 6;
    const int l15  = lane & 15;
    const int grp  = lane >> 4;                       // 0..3
    const int wbase = blockIdx.x * 64 + wid * 16;

    // --- coalesced gather: stage[row] = bf16(fni[src[e]] + fnj[dst[e]]) ---
    #pragma unroll
    for (int it = 0; it < 2; it++) {
        const int row = it * 8 + (lane >> 3);         // 0..15
        const int e = wbase + row;
        const int c8 = (lane & 7) * 8;
        const u16x8 a = *reinterpret_cast<const u16x8*>(fni + (u32)(src[e] * FE + c8));
        const u16x8 b = *reinterpret_cast<const u16x8*>(fnj + (u32)(dst[e] * FE + c8));
        u32x4 s;
        #pragma unroll
        for (int j = 0; j < 4; j++) {
            s[j] = cvt2bf(bf2f(a[2*j]) + bf2f(b[2*j]),
                          bf2f(a[2*j+1]) + bf2f(b[2*j+1]));
        }
        *reinterpret_cast<u32x4*>(&stage[wid][row][c8]) = s;
    }

    // --- A fragments: row = wbase+l15, k = half*32 + grp*8 + j ---
    bf16x8 afr0, afr1;
    if constexpr (FIRST) {
        const float2 xx = *reinterpret_cast<const float2*>(x + 2 * (u32)(wbase + l15));
        #pragma unroll
        for (int half = 0; half < 2; half++) {
            const int c0 = half * 32 + grp * 8;
            const float4 wA0 = *reinterpret_cast<const float4*>(Win + c0);
            const float4 wA1 = *reinterpret_cast<const float4*>(Win + c0 + 4);
            const float4 wB0 = *reinterpret_cast<const float4*>(Win + FE + c0);
            const float4 wB1 = *reinterpret_cast<const float4*>(Win + FE + c0 + 4);
            const float4 b0  = *reinterpret_cast<const float4*>(bin + c0);
            const float4 b1  = *reinterpret_cast<const float4*>(bin + c0 + 4);
            u32x4 fr;
            fr[0] = cvt2bf(fmaf(xx.x, wA0.x, fmaf(xx.y, wB0.x, b0.x)),
                           fmaf(xx.x, wA0.y, fmaf(xx.y, wB0.y, b0.y)));
            fr[1] = cvt2bf(fmaf(xx.x, wA0.z, fmaf(xx.y, wB0.z, b0.z)),
                           fmaf(xx.x, wA0.w, fmaf(xx.y, wB0.w, b0.w)));
            fr[2] = cvt2bf(fmaf(xx.x, wA1.x, fmaf(xx.y, wB1.x, b1.x)),
                           fmaf(xx.x, wA1.y, fmaf(xx.y, wB1.y, b1.y)));
            fr[3] = cvt2bf(fmaf(xx.x, wA1.z, fmaf(xx.y, wB1.z, b1.z)),
                           fmaf(xx.x, wA1.w, fmaf(xx.y, wB1.w, b1.w)));
            if (half == 0) afr0 = (bf16x8)fr; else afr1 = (bf16x8)fr;
        }
    } else {
        const u32 arow = (u32)(wbase + l15) * FE;
        afr0 = *reinterpret_cast<const bf16x8*>(ef + arow + grp * 8);
        afr1 = *reinterpret_cast<const bf16x8*>(ef + arow + 32 + grp * 8);
    }

    // --- B fragments: Wt[n][k]; n = nt*16+l15, k = ks*32+grp*8+j ---
    bf16x8 bfr[2][4];
    #pragma unroll
    for (int ks = 0; ks < 2; ks++)
        #pragma unroll
        for (int nt = 0; nt < 4; nt++)
            bfr[ks][nt] = *reinterpret_cast<const bf16x8*>(
                Wt + (u32)((nt * 16 + l15) * 64 + ks * 32 + grp * 8));

    f32x4 acc[4];
    #pragma unroll
    for (int nt = 0; nt < 4; nt++) {
        acc[nt] = (f32x4){0.f, 0.f, 0.f, 0.f};
        acc[nt] = __builtin_amdgcn_mfma_f32_16x16x32_bf16(afr0, bfr[0][nt], acc[nt], 0, 0, 0);
        acc[nt] = __builtin_amdgcn_mfma_f32_16x16x32_bf16(afr1, bfr[1][nt], acc[nt], 0, 0, 0);
    }

    // attn pre-scaled by log2(e): logit sum feeds exp2 (native v_exp_f32)
    float an[4];
    #pragma unroll
    for (int nt = 0; nt < 4; nt++) an[nt] = attn[nt * 16 + l15] * 1.44269504088896f;

    __builtin_amdgcn_wave_barrier();   // stage writes <-> epilogue reads

    // --- epilogue: add staged sum, leaky_relu, logit partials, f_out→LDS ---
    float logit[4] = {0.f, 0.f, 0.f, 0.f};
    #pragma unroll
    for (int nt = 0; nt < 4; nt++) {
        const int n = nt * 16 + l15;
        #pragma unroll
        for (int r = 0; r < 4; r++) {
            const int row = grp * 4 + r;              // edge slot in wave
            float v = acc[nt][r] + bf2f(stage[wid][row][n]);
            v = fmaxf(v, 0.2f * v);                   // leaky_relu(0.2)
            logit[r] = fmaf(v, an[nt], logit[r]);
            if constexpr (WRITE_EF) fol[wid][row][n] = f2bf(v);
        }
    }

    // --- logit reduce (16 lanes/edge) + direct scatter into S ---
    #pragma unroll
    for (int r = 0; r < 4; r++) {
        float t = logit[r];
        t += __shfl_xor(t, 1, 16);
        t += __shfl_xor(t, 2, 16);
        t += __shfl_xor(t, 4, 16);
        t += __shfl_xor(t, 8, 16);
        if (l15 == 0) {
            const int e = wbase + grp * 4 + r;
            atomicAdd(S + (u32)(dst[e] * N_NODES + src[e]), exp2f(t));
        }
    }

    // --- ef write-back from A-frag registers + fol LDS (A layout: row=l15,
    //     cols grp*8.. and 32+grp*8..), 16B stores ---
    if constexpr (WRITE_EF) {
        __builtin_amdgcn_wave_barrier();   // fol writes <-> fol reads
        const u16x8 fo0 = *reinterpret_cast<const u16x8*>(&fol[wid][l15][grp * 8]);
        const u16x8 fo1 = *reinterpret_cast<const u16x8*>(&fol[wid][l15][32 + grp * 8]);
        u32x4 o0, o1;
        #pragma unroll
        for (int j = 0; j < 4; j++) {
            o0[j] = cvt2bf(bf2f((u16)afr0[2*j])   + bf2f(fo0[2*j]),
                           bf2f((u16)afr0[2*j+1]) + bf2f(fo0[2*j+1]));
            o1[j] = cvt2bf(bf2f((u16)afr1[2*j])   + bf2f(fo1[2*j]),
                           bf2f((u16)afr1[2*j+1]) + bf2f(fo1[2*j+1]));
        }
        u16* gp = ef + (u32)(wbase + l15) * FE;
        *reinterpret_cast<u32x4*>(gp + grp * 8) = o0;
        *reinterpret_cast<u32x4*>(gp + 32 + grp * 8) = o1;
    }
}

// ---------------------------------------------------------------------------
// spmm (+fusions): nout = nin + (S@h)/rowsum(S).  For !LAST additionally:
// re-zero S row, write nodeA, next-layer projections (h double-buffered).
// r10: 4-way accumulator ILP breaks the 512-deep fma chain.
// ---------------------------------------------------------------------------
template <bool LAST>
__global__ __launch_bounds__(256) void spmm_kernel(
    float* __restrict__ S, const float* __restrict__ h,
    const float* __restrict__ nin, float* __restrict__ nout,
    const float* __restrict__ Wni, const float* __restrict__ Wnj,
    const float* __restrict__ Wnode, const float* __restrict__ bias,
    u16* __restrict__ fni, u16* __restrict__ fnj, float* __restrict__ hnext)
{
    __shared__ float red[256];
    __shared__ float rs[2];
    __shared__ float row[FC];
    const int d = blockIdx.x;
    const int t = threadIdx.x;
    const int c = t & 127;
    const int half = t >> 7;
    const float* Srow = S + (size_t)d * N_NODES + half * 512;
    const float* hp = h + (size_t)half * 512 * FC;
    float a0 = 0.f, a1 = 0.f, a2 = 0.f, a3 = 0.f;
    float r0 = 0.f, r1 = 0.f, r2 = 0.f, r3 = 0.f;
    #pragma unroll 4
    for (int n = 0; n < 512; n += 4) {
        const float s0 = Srow[n], s1 = Srow[n+1], s2 = Srow[n+2], s3 = Srow[n+3];
        r0 += s0; r1 += s1; r2 += s2; r3 += s3;
        a0 = fmaf(s0, hp[n * FC + c], a0);
        a1 = fmaf(s1, hp[(n+1) * FC + c], a1);
        a2 = fmaf(s2, hp[(n+2) * FC + c], a2);
        a3 = fmaf(s3, hp[(n+3) * FC + c], a3);
    }
    red[t] = (a0 + a1) + (a2 + a3);
    if (c == 0) rs[half] = (r0 + r1) + (r2 + r3);
    __syncthreads();

    if constexpr (!LAST) {   // re-zero S row for next layer (reads done)
        reinterpret_cast<float4*>(S + (size_t)d * N_NODES)[t] = make_float4(0.f, 0.f, 0.f, 0.f);
    }
    if (half == 0) {
        const float v = nin[d * FC + c] + (red[c] + red[128 + c]) / (rs[0] + rs[1]);
        nout[d * FC + c] = v;
        if constexpr (!LAST) row[c] = v;
    }

    if constexpr (!LAST) {
        __syncthreads();
        if (t < 64) {
            float b0 = 0.f, b1 = 0.f;
            #pragma unroll 8
            for (int k = 0; k < FC; k += 2) {
                b0 = fmaf(row[k],     Wni[k * FE + t], b0);
                b1 = fmaf(row[k + 1], Wni[(k + 1) * FE + t], b1);
            }
            fni[d * FE + t] = f2bf(b0 + b1);
        } else if (t < 128) {
            const int f = t - 64;
            float b0 = 0.f, b1 = 0.f;
            #pragma unroll 8
            for (int k = 0; k < FC; k += 2) {
                b0 = fmaf(row[k],     Wnj[k * FE + f], b0);
                b1 = fmaf(row[k + 1], Wnj[(k + 1) * FE + f], b1);
            }
            fnj[d * FE + f] = f2bf(b0 + b1);
        } else {
            const int cc = t - 128;
            float b0 = bias[cc], b1 = 0.f;
            #pragma unroll 8
            for (int k = 0; k < FC; k += 2) {
                b0 = fmaf(row[k],     Wnode[k * FC + cc], b0);
                b1 = fmaf(row[k + 1], Wnode[(k + 1) * FC + cc], b1);
            }
            hnext[d * FC + cc] = b0 + b1;
        }
    }
}

// ---------------------------------------------------------------------------
extern "C" void kernel_launch(void* const* d_in, const int* in_sizes, int n_in,
                              void* d_out, int out_size, void* d_ws, size_t ws_size,
                              hipStream_t stream)
{
    const float* node_feature = (const float*)d_in[0];
    const float* edge_feature = (const float*)d_in[1];
    const int*   src          = (const int*)d_in[2];
    const int*   dst          = (const int*)d_in[3];
    const float* W_in         = (const float*)d_in[4];
    const float* b_in         = (const float*)d_in[5];
    const float* W_ni         = (const float*)d_in[6];
    const float* W_nj         = (const float*)d_in[7];
    const float* W_fij        = (const float*)d_in[8];
    const float* W_node       = (const float*)d_in[9];
    const float* attn         = (const float*)d_in[10];
    const float* bias_node    = (const float*)d_in[11];
    float* out = (float*)d_out;

    char* ws = (char*)d_ws;
    size_t off = 0;
    auto alloc = [&](size_t bytes) -> void* {
        void* pp = ws + off;
        off += (bytes + 255) & ~(size_t)255;
        return pp;
    };
    u16*   ef    = (u16*)alloc((size_t)E_EDGES * FE * sizeof(u16));       // 67 MB
    u16*   fni   = (u16*)alloc(N_NODES * FE * sizeof(u16));
    u16*   fnj   = (u16*)alloc(N_NODES * FE * sizeof(u16));
    float* h0    = (float*)alloc(N_NODES * FC * sizeof(float));
    float* h1    = (float*)alloc(N_NODES * FC * sizeof(float));
    float* S     = (float*)alloc((size_t)N_NODES * N_NODES * sizeof(float)); // 4 MB
    float* nodeA = (float*)alloc(N_NODES * FC * sizeof(float));
    u16*   Wt    = (u16*)alloc((size_t)NLAYERS * FE * FE * sizeof(u16));  // 24 KB
    float* hbuf[2] = {h0, h1};

    setup_kernel<<<N_NODES, 256, 0, stream>>>(
        node_feature, W_fij, Wt, W_ni, W_nj, W_node, bias_node,
        fni, fnj, h0, S, nodeA);

    for (int l = 0; l < NLAYERS; l++) {
        float* hl = hbuf[l & 1];
        float* hn = hbuf[(l + 1) & 1];

        if (l == 0) {
            edge_mfma_kernel<true, true><<<E_EDGES / 64, 256, 0, stream>>>(
                ef, edge_feature, W_in, b_in, Wt + (size_t)l * FE * FE,
                fni, fnj, src, dst, attn + (size_t)l * FE, S);
        } else if (l == NLAYERS - 1) {
            edge_mfma_kernel<false, false><<<E_EDGES / 64, 256, 0, stream>>>(
                ef, nullptr, nullptr, nullptr, Wt + (size_t)l * FE * FE,
                fni, fnj, src, dst, attn + (size_t)l * FE, S);
        } else {
            edge_mfma_kernel<false, true><<<E_EDGES / 64, 256, 0, stream>>>(
                ef, nullptr, nullptr, nullptr, Wt + (size_t)l * FE * FE,
                fni, fnj, src, dst, attn + (size_t)l * FE, S);
        }

        if (l == NLAYERS - 1) {
            spmm_kernel<true><<<N_NODES, 256, 0, stream>>>(
                S, hl, nodeA, out,
                nullptr, nullptr, nullptr, nullptr, nullptr, nullptr, nullptr);
        } else {
            const int ln = l + 1;
            spmm_kernel<false><<<N_NODES, 256, 0, stream>>>(
                S, hl, nodeA, nodeA,
                W_ni + (size_t)ln * FC * FE, W_nj + (size_t)ln * FC * FE,
                W_node + (size_t)ln * FC * FC, bias_node + (size_t)ln * FC,
                fni, fnj, hn);
        }
    }
}

// Round 12
// 272.136 us; speedup vs baseline: 1.3996x; 1.0290x over previous
//
#include <hip/hip_runtime.h>

#define N_NODES 1024
#define E_EDGES 524288
#define FE 64
#define FC 128
#define NLAYERS 3

typedef unsigned short u16;
typedef unsigned int u32;
typedef __attribute__((ext_vector_type(8))) short bf16x8;   // MFMA A/B frag
typedef __attribute__((ext_vector_type(4))) float f32x4;    // MFMA C/D frag
typedef __attribute__((ext_vector_type(8))) unsigned short u16x8;
typedef __attribute__((ext_vector_type(4))) unsigned int u32x4;

__device__ __forceinline__ float bf2f(u16 u) {
    return __uint_as_float(((u32)u) << 16);
}
__device__ __forceinline__ u32 cvt2bf(float lo, float hi) {
    u32 r;
    asm("v_cvt_pk_bf16_f32 %0, %1, %2" : "=v"(r) : "v"(lo), "v"(hi));
    return r;
}
__device__ __forceinline__ u16 f2bf(float f) {
    return (u16)cvt2bf(f, 0.f);
}

// ---------------------------------------------------------------------------
// Setup (1024 blocks, one per node): zero S row, copy node->nodeA, transpose
// W_fij into bf16 Wt (blocks 0..47), and layer-0 projections fni/fnj/h.
// ---------------------------------------------------------------------------
__global__ __launch_bounds__(256) void setup_kernel(
    const float* __restrict__ node_feature, const float* __restrict__ Wfij,
    u16* __restrict__ Wt,
    const float* __restrict__ Wni, const float* __restrict__ Wnj,
    const float* __restrict__ Wnode, const float* __restrict__ bias,
    u16* __restrict__ fni, u16* __restrict__ fnj,
    float* __restrict__ h, float* __restrict__ S, float* __restrict__ nodeA)
{
    __shared__ float row[FC];
    const int d = blockIdx.x;
    const int t = threadIdx.x;

    reinterpret_cast<float4*>(S + (size_t)d * N_NODES)[t] = make_float4(0.f, 0.f, 0.f, 0.f);

    if (t < FC) {
        const float v = node_feature[d * FC + t];
        nodeA[d * FC + t] = v;
        row[t] = v;
    }
    if (d < (NLAYERS * FE * FE) / 256) {
        const int i = d * 256 + t;
        const int l = i >> 12, rem = i & 4095;
        const int n = rem >> 6, k = rem & 63;
        Wt[(u32)(l * 4096 + n * 64 + k)] = f2bf(Wfij[(u32)(l * 4096 + k * 64 + n)]);
    }
    __syncthreads();

    if (t < 64) {
        float a0 = 0.f, a1 = 0.f;
        #pragma unroll 8
        for (int k = 0; k < FC; k += 2) {
            a0 = fmaf(row[k],     Wni[k * FE + t], a0);
            a1 = fmaf(row[k + 1], Wni[(k + 1) * FE + t], a1);
        }
        fni[d * FE + t] = f2bf(a0 + a1);
    } else if (t < 128) {
        const int f = t - 64;
        float a0 = 0.f, a1 = 0.f;
        #pragma unroll 8
        for (int k = 0; k < FC; k += 2) {
            a0 = fmaf(row[k],     Wnj[k * FE + f], a0);
            a1 = fmaf(row[k + 1], Wnj[(k + 1) * FE + f], a1);
        }
        fnj[d * FE + f] = f2bf(a0 + a1);
    } else {
        const int c = t - 128;
        float a0 = bias[c], a1 = 0.f;
        #pragma unroll 8
        for (int k = 0; k < FC; k += 2) {
            a0 = fmaf(row[k],     Wnode[k * FC + c], a0);
            a1 = fmaf(row[k + 1], Wnode[(k + 1) * FC + c], a1);
        }
        h[d * FC + c] = a0 + a1;
    }
}

// ---------------------------------------------------------------------------
// MFMA edge kernel, 2-TILE PIPELINED (r11/r12). Block = 4 waves x 2 tiles of
// 16 edges (128 edges/block, grid E/128). All loads for BOTH tiles issued up
// front -> 2x memory-level parallelism per wave (r10: latency-bound, all
// pipes <35%). stage/fol LDS reused across tiles (wave-local; wave_barrier
// pins order).
// r12 fix: sidx/didx shuffles hoisted OUT of the divergent l15==0 branch —
// __shfl from inactive lanes is undefined (r11 correctness failure).
// Per tile:
//   F = EF[16x64] @ W[64x64];  f = leaky_relu(F + staged(fni[src]+fnj[dst]))
//   ef' += f (bf16, fol LDS transpose + A-frag regs); S[dst][src] += exp2(f.a)
// Fragment layouts (m89 family):
//   A: row=lane&15 (edge), k=(lane>>4)*8+j     B: col=lane&15 (n), same k
//   C: col=lane&15 (n),  row=(lane>>4)*4+reg   (edge)
// ---------------------------------------------------------------------------
template <bool FIRST, bool WRITE_EF>
__global__ void edge_mfma_kernel(
    u16* __restrict__ ef,                 // [E][64] bf16 (in/out)
    const float* __restrict__ x,          // [E][2]   (FIRST only)
    const float* __restrict__ Win,        // [2][64]  (FIRST only)
    const float* __restrict__ bin,        // [64]     (FIRST only)
    const u16* __restrict__ Wt,           // [64 n][64 k] bf16 (this layer)
    const u16* __restrict__ fni, const u16* __restrict__ fnj,
    const int* __restrict__ src, const int* __restrict__ dst,
    const float* __restrict__ attn,       // [64] fp32
    float* __restrict__ S)                // [N][N] fp32 (pre-zeroed)
{
    __shared__ __align__(16) u16 stage[4][16][72];               // fni+fnj sum
    __shared__ __align__(16) u16 fol[WRITE_EF ? 4 : 1][16][72];  // f_out rows

    const int lane = threadIdx.x & 63;
    const int wid  = threadIdx.x >> 6;
    const int l15  = lane & 15;
    const int grp  = lane >> 4;                       // 0..3
    const int block0 = blockIdx.x * 128;

    // --- issue ALL loads for both tiles up front (MLP) ---
    int tb[2], sv[2], dv[2];
    #pragma unroll
    for (int tt = 0; tt < 2; tt++) {
        tb[tt] = block0 + tt * 64 + wid * 16;
        sv[tt] = src[tb[tt] + l15];
        dv[tt] = dst[tb[tt] + l15];
    }

    u16x8 ga[2][2], gb[2][2];
    #pragma unroll
    for (int tt = 0; tt < 2; tt++) {
        #pragma unroll
        for (int it = 0; it < 2; it++) {
            const int row = it * 8 + (lane >> 3);     // 0..15
            const int c8 = (lane & 7) * 8;
            const int s = __shfl(sv[tt], row, 16);
            const int d = __shfl(dv[tt], row, 16);
            ga[tt][it] = *reinterpret_cast<const u16x8*>(fni + (u32)(s * FE + c8));
            gb[tt][it] = *reinterpret_cast<const u16x8*>(fnj + (u32)(d * FE + c8));
        }
    }

    bf16x8 afr[2][2];       // [tile][half]
    #pragma unroll
    for (int tt = 0; tt < 2; tt++) {
        if constexpr (FIRST) {
            const float2 xx = *reinterpret_cast<const float2*>(x + 2 * (u32)(tb[tt] + l15));
            #pragma unroll
            for (int half = 0; half < 2; half++) {
                const int c0 = half * 32 + grp * 8;
                const float4 wA0 = *reinterpret_cast<const float4*>(Win + c0);
                const float4 wA1 = *reinterpret_cast<const float4*>(Win + c0 + 4);
                const float4 wB0 = *reinterpret_cast<const float4*>(Win + FE + c0);
                const float4 wB1 = *reinterpret_cast<const float4*>(Win + FE + c0 + 4);
                const float4 b0  = *reinterpret_cast<const float4*>(bin + c0);
                const float4 b1  = *reinterpret_cast<const float4*>(bin + c0 + 4);
                u32x4 fr;
                fr[0] = cvt2bf(fmaf(xx.x, wA0.x, fmaf(xx.y, wB0.x, b0.x)),
                               fmaf(xx.x, wA0.y, fmaf(xx.y, wB0.y, b0.y)));
                fr[1] = cvt2bf(fmaf(xx.x, wA0.z, fmaf(xx.y, wB0.z, b0.z)),
                               fmaf(xx.x, wA0.w, fmaf(xx.y, wB0.w, b0.w)));
                fr[2] = cvt2bf(fmaf(xx.x, wA1.x, fmaf(xx.y, wB1.x, b1.x)),
                               fmaf(xx.x, wA1.y, fmaf(xx.y, wB1.y, b1.y)));
                fr[3] = cvt2bf(fmaf(xx.x, wA1.z, fmaf(xx.y, wB1.z, b1.z)),
                               fmaf(xx.x, wA1.w, fmaf(xx.y, wB1.w, b1.w)));
                afr[tt][half] = (bf16x8)fr;
            }
        } else {
            const u32 arow = (u32)(tb[tt] + l15) * FE;
            afr[tt][0] = *reinterpret_cast<const bf16x8*>(ef + arow + grp * 8);
            afr[tt][1] = *reinterpret_cast<const bf16x8*>(ef + arow + 32 + grp * 8);
        }
    }

    // --- B fragments: Wt[n][k]; n = nt*16+l15, k = ks*32+grp*8+j ---
    bf16x8 bfr[2][4];
    #pragma unroll
    for (int ks = 0; ks < 2; ks++)
        #pragma unroll
        for (int nt = 0; nt < 4; nt++)
            bfr[ks][nt] = *reinterpret_cast<const bf16x8*>(
                Wt + (u32)((nt * 16 + l15) * 64 + ks * 32 + grp * 8));

    float an[4];
    #pragma unroll
    for (int nt = 0; nt < 4; nt++) an[nt] = attn[nt * 16 + l15] * 1.44269504088896f;

    // --- process tiles sequentially, reusing stage/fol ---
    #pragma unroll
    for (int tt = 0; tt < 2; tt++) {
        // stage write: bf16(fni[src]+fnj[dst]) for this tile's 16 rows
        #pragma unroll
        for (int it = 0; it < 2; it++) {
            const int row = it * 8 + (lane >> 3);
            const int c8 = (lane & 7) * 8;
            u32x4 s;
            #pragma unroll
            for (int j = 0; j < 4; j++) {
                s[j] = cvt2bf(bf2f(ga[tt][it][2*j])   + bf2f(gb[tt][it][2*j]),
                              bf2f(ga[tt][it][2*j+1]) + bf2f(gb[tt][it][2*j+1]));
            }
            *reinterpret_cast<u32x4*>(&stage[wid][row][c8]) = s;
        }

        f32x4 acc[4];
        #pragma unroll
        for (int nt = 0; nt < 4; nt++) {
            acc[nt] = (f32x4){0.f, 0.f, 0.f, 0.f};
            acc[nt] = __builtin_amdgcn_mfma_f32_16x16x32_bf16(afr[tt][0], bfr[0][nt], acc[nt], 0, 0, 0);
            acc[nt] = __builtin_amdgcn_mfma_f32_16x16x32_bf16(afr[tt][1], bfr[1][nt], acc[nt], 0, 0, 0);
        }

        __builtin_amdgcn_wave_barrier();   // stage writes <-> epilogue reads

        float logit[4] = {0.f, 0.f, 0.f, 0.f};
        #pragma unroll
        for (int nt = 0; nt < 4; nt++) {
            const int n = nt * 16 + l15;
            #pragma unroll
            for (int r = 0; r < 4; r++) {
                const int row = grp * 4 + r;          // edge slot in wave
                float v = acc[nt][r] + bf2f(stage[wid][row][n]);
                v = fmaxf(v, 0.2f * v);               // leaky_relu(0.2)
                logit[r] = fmaf(v, an[nt], logit[r]);
                if constexpr (WRITE_EF) fol[wid][row][n] = f2bf(v);
            }
        }

        // logit reduce (16 lanes/edge) + direct scatter into S.
        // sidx/didx shuffles are exec-full (hoisted; r11 bug was shfl inside
        // the divergent branch -> undefined reads from inactive lanes).
        #pragma unroll
        for (int r = 0; r < 4; r++) {
            float t = logit[r];
            t += __shfl_xor(t, 1, 16);
            t += __shfl_xor(t, 2, 16);
            t += __shfl_xor(t, 4, 16);
            t += __shfl_xor(t, 8, 16);
            const int sidx = __shfl(sv[tt], grp * 4 + r, 16);
            const int didx = __shfl(dv[tt], grp * 4 + r, 16);
            if (l15 == 0) {
                atomicAdd(S + (u32)(didx * N_NODES + sidx), exp2f(t));
            }
        }

        if constexpr (WRITE_EF) {
            __builtin_amdgcn_wave_barrier();   // fol writes <-> fol reads
            const u16x8 fo0 = *reinterpret_cast<const u16x8*>(&fol[wid][l15][grp * 8]);
            const u16x8 fo1 = *reinterpret_cast<const u16x8*>(&fol[wid][l15][32 + grp * 8]);
            u32x4 o0, o1;
            #pragma unroll
            for (int j = 0; j < 4; j++) {
                o0[j] = cvt2bf(bf2f((u16)afr[tt][0][2*j])   + bf2f(fo0[2*j]),
                               bf2f((u16)afr[tt][0][2*j+1]) + bf2f(fo0[2*j+1]));
                o1[j] = cvt2bf(bf2f((u16)afr[tt][1][2*j])   + bf2f(fo1[2*j]),
                               bf2f((u16)afr[tt][1][2*j+1]) + bf2f(fo1[2*j+1]));
            }
            u16* gp = ef + (u32)(tb[tt] + l15) * FE;
            *reinterpret_cast<u32x4*>(gp + grp * 8) = o0;
            *reinterpret_cast<u32x4*>(gp + 32 + grp * 8) = o1;
        }

        __builtin_amdgcn_wave_barrier();   // protect stage/fol reuse by tile 1
    }
}

// ---------------------------------------------------------------------------
// spmm v2 (r11): 4 dst rows per block (grid N/4). S reads are wave-uniform
// -> scalar loads; h read once per block (64 MB/dispatch vs 512 MB at 1-row).
// rowsum via separate vectorized pass + wave reduce.
// For !LAST: re-zero 4 S rows, write nodeA, next-layer projections.
// ---------------------------------------------------------------------------
template <bool LAST>
__global__ __launch_bounds__(256) void spmm_kernel(
    float* __restrict__ S, const float* __restrict__ h,
    const float* __restrict__ nin, float* __restrict__ nout,
    const float* __restrict__ Wni, const float* __restrict__ Wnj,
    const float* __restrict__ Wnode, const float* __restrict__ bias,
    u16* __restrict__ fni, u16* __restrict__ fnj, float* __restrict__ hnext)
{
    __shared__ float red[2][128][4];
    __shared__ float rs[4];
    __shared__ float row[4][FC];
    const int d0 = blockIdx.x * 4;
    const int t = threadIdx.x;
    const int c = t & 127;
    const int half = t >> 7;

    const float* hp = h + (u32)(half * 512 * FC) + c;
    const u32 sbase = (u32)(d0 * N_NODES) + half * 512;
    float a0 = 0.f, a1 = 0.f, a2 = 0.f, a3 = 0.f;
    #pragma unroll 4
    for (int n = 0; n < 512; n++) {
        const float hv = hp[(u32)n * FC];
        const float s0 = S[sbase + n];
        const float s1 = S[sbase + N_NODES + n];
        const float s2 = S[sbase + 2 * N_NODES + n];
        const float s3 = S[sbase + 3 * N_NODES + n];
        a0 = fmaf(s0, hv, a0);
        a1 = fmaf(s1, hv, a1);
        a2 = fmaf(s2, hv, a2);
        a3 = fmaf(s3, hv, a3);
    }
    red[half][c][0] = a0; red[half][c][1] = a1;
    red[half][c][2] = a2; red[half][c][3] = a3;

    // rowsum pass: wave w sums row d0+w (1024 floats as 4x float4/lane)
    {
        const int w = t >> 6, wl = t & 63;
        const float4* sr = reinterpret_cast<const float4*>(S + (u32)(d0 + w) * N_NODES);
        float rsv = 0.f;
        #pragma unroll
        for (int q = 0; q < 4; q++) {
            const float4 v = sr[wl + 64 * q];
            rsv += (v.x + v.y) + (v.z + v.w);
        }
        rsv += __shfl_xor(rsv, 1);  rsv += __shfl_xor(rsv, 2);
        rsv += __shfl_xor(rsv, 4);  rsv += __shfl_xor(rsv, 8);
        rsv += __shfl_xor(rsv, 16); rsv += __shfl_xor(rsv, 32);
        if (wl == 0) rs[w] = rsv;
    }
    __syncthreads();

    if constexpr (!LAST) {   // re-zero the 4 S rows (reads done)
        float4* sz = reinterpret_cast<float4*>(S + (u32)d0 * N_NODES);
        #pragma unroll
        for (int q = 0; q < 4; q++) sz[t + 256 * q] = make_float4(0.f, 0.f, 0.f, 0.f);
    }
    if (t < 128) {
        #pragma unroll
        for (int r = 0; r < 4; r++) {
            const float v = nin[(u32)(d0 + r) * FC + t]
                          + (red[0][t][r] + red[1][t][r]) / rs[r];
            nout[(u32)(d0 + r) * FC + t] = v;
            if constexpr (!LAST) row[r][t] = v;
        }
    }

    if constexpr (!LAST) {
        __syncthreads();
        if (t < 64) {
            #pragma unroll
            for (int r = 0; r < 4; r++) {
                float b0 = 0.f, b1 = 0.f;
                #pragma unroll 8
                for (int k = 0; k < FC; k += 2) {
                    b0 = fmaf(row[r][k],     Wni[k * FE + t], b0);
                    b1 = fmaf(row[r][k + 1], Wni[(k + 1) * FE + t], b1);
                }
                fni[(u32)(d0 + r) * FE + t] = f2bf(b0 + b1);
            }
        } else if (t < 128) {
            const int f = t - 64;
            #pragma unroll
            for (int r = 0; r < 4; r++) {
                float b0 = 0.f, b1 = 0.f;
                #pragma unroll 8
                for (int k = 0; k < FC; k += 2) {
                    b0 = fmaf(row[r][k],     Wnj[k * FE + f], b0);
                    b1 = fmaf(row[r][k + 1], Wnj[(k + 1) * FE + f], b1);
                }
                fnj[(u32)(d0 + r) * FE + f] = f2bf(b0 + b1);
            }
        } else {
            const int cc = t - 128;
            #pragma unroll
            for (int r = 0; r < 4; r++) {
                float b0 = bias[cc], b1 = 0.f;
                #pragma unroll 8
                for (int k = 0; k < FC; k += 2) {
                    b0 = fmaf(row[r][k],     Wnode[k * FC + cc], b0);
                    b1 = fmaf(row[r][k + 1], Wnode[(k + 1) * FC + cc], b1);
                }
                hnext[(u32)(d0 + r) * FC + cc] = b0 + b1;
            }
        }
    }
}

// ---------------------------------------------------------------------------
extern "C" void kernel_launch(void* const* d_in, const int* in_sizes, int n_in,
                              void* d_out, int out_size, void* d_ws, size_t ws_size,
                              hipStream_t stream)
{
    const float* node_feature = (const float*)d_in[0];
    const float* edge_feature = (const float*)d_in[1];
    const int*   src          = (const int*)d_in[2];
    const int*   dst          = (const int*)d_in[3];
    const float* W_in         = (const float*)d_in[4];
    const float* b_in         = (const float*)d_in[5];
    const float* W_ni         = (const float*)d_in[6];
    const float* W_nj         = (const float*)d_in[7];
    const float* W_fij        = (const float*)d_in[8];
    const float* W_node       = (const float*)d_in[9];
    const float* attn         = (const float*)d_in[10];
    const float* bias_node    = (const float*)d_in[11];
    float* out = (float*)d_out;

    char* ws = (char*)d_ws;
    size_t off = 0;
    auto alloc = [&](size_t bytes) -> void* {
        void* pp = ws + off;
        off += (bytes + 255) & ~(size_t)255;
        return pp;
    };
    u16*   ef    = (u16*)alloc((size_t)E_EDGES * FE * sizeof(u16));       // 67 MB
    u16*   fni   = (u16*)alloc(N_NODES * FE * sizeof(u16));
    u16*   fnj   = (u16*)alloc(N_NODES * FE * sizeof(u16));
    float* h0    = (float*)alloc(N_NODES * FC * sizeof(float));
    float* h1    = (float*)alloc(N_NODES * FC * sizeof(float));
    float* S     = (float*)alloc((size_t)N_NODES * N_NODES * sizeof(float)); // 4 MB
    float* nodeA = (float*)alloc(N_NODES * FC * sizeof(float));
    u16*   Wt    = (u16*)alloc((size_t)NLAYERS * FE * FE * sizeof(u16));  // 24 KB
    float* hbuf[2] = {h0, h1};

    setup_kernel<<<N_NODES, 256, 0, stream>>>(
        node_feature, W_fij, Wt, W_ni, W_nj, W_node, bias_node,
        fni, fnj, h0, S, nodeA);

    for (int l = 0; l < NLAYERS; l++) {
        float* hl = hbuf[l & 1];
        float* hn = hbuf[(l + 1) & 1];

        if (l == 0) {
            edge_mfma_kernel<true, true><<<E_EDGES / 128, 256, 0, stream>>>(
                ef, edge_feature, W_in, b_in, Wt + (size_t)l * FE * FE,
                fni, fnj, src, dst, attn + (size_t)l * FE, S);
        } else if (l == NLAYERS - 1) {
            edge_mfma_kernel<false, false><<<E_EDGES / 128, 256, 0, stream>>>(
                ef, nullptr, nullptr, nullptr, Wt + (size_t)l * FE * FE,
                fni, fnj, src, dst, attn + (size_t)l * FE, S);
        } else {
            edge_mfma_kernel<false, true><<<E_EDGES / 128, 256, 0, stream>>>(
                ef, nullptr, nullptr, nullptr, Wt + (size_t)l * FE * FE,
                fni, fnj, src, dst, attn + (size_t)l * FE, S);
        }

        if (l == NLAYERS - 1) {
            spmm_kernel<true><<<N_NODES / 4, 256, 0, stream>>>(
                S, hl, nodeA, out,
                nullptr, nullptr, nullptr, nullptr, nullptr, nullptr, nullptr);
        } else {
            const int ln = l + 1;
            spmm_kernel<false><<<N_NODES / 4, 256, 0, stream>>>(
                S, hl, nodeA, nodeA,
                W_ni + (size_t)ln * FC * FE, W_nj + (size_t)ln * FC * FE,
                W_node + (size_t)ln * FC * FC, bias_node + (size_t)ln * FC,
                fni, fnj, hn);
        }
    }
}

// Round 13
// 233.603 us; speedup vs baseline: 1.6305x; 1.1650x over previous
//
#include <hip/hip_runtime.h>

#define N_NODES 1024
#define E_EDGES 524288
#define FE 64
#define FC 128
#define NLAYERS 3

typedef unsigned short u16;
typedef unsigned int u32;
typedef __attribute__((ext_vector_type(8))) short bf16x8;   // MFMA A/B frag
typedef __attribute__((ext_vector_type(4))) float f32x4;    // MFMA C/D frag
typedef __attribute__((ext_vector_type(8))) unsigned short u16x8;
typedef __attribute__((ext_vector_type(4))) unsigned int u32x4;

__device__ __forceinline__ float bf2f(u16 u) {
    return __uint_as_float(((u32)u) << 16);
}
__device__ __forceinline__ u32 cvt2bf(float lo, float hi) {
    u32 r;
    asm("v_cvt_pk_bf16_f32 %0, %1, %2" : "=v"(r) : "v"(lo), "v"(hi));
    return r;
}
__device__ __forceinline__ u16 f2bf(float f) {
    return (u16)cvt2bf(f, 0.f);
}

// ---------------------------------------------------------------------------
// Setup (1024 blocks, one per node): zero S row, copy node->nodeA, transpose
// W_fij into bf16 Wt (blocks 0..47), and layer-0 projections fni/fnj/h.
// ---------------------------------------------------------------------------
__global__ __launch_bounds__(256) void setup_kernel(
    const float* __restrict__ node_feature, const float* __restrict__ Wfij,
    u16* __restrict__ Wt,
    const float* __restrict__ Wni, const float* __restrict__ Wnj,
    const float* __restrict__ Wnode, const float* __restrict__ bias,
    u16* __restrict__ fni, u16* __restrict__ fnj,
    float* __restrict__ h, float* __restrict__ S, float* __restrict__ nodeA)
{
    __shared__ float row[FC];
    const int d = blockIdx.x;
    const int t = threadIdx.x;

    reinterpret_cast<float4*>(S + (size_t)d * N_NODES)[t] = make_float4(0.f, 0.f, 0.f, 0.f);

    if (t < FC) {
        const float v = node_feature[d * FC + t];
        nodeA[d * FC + t] = v;
        row[t] = v;
    }
    if (d < (NLAYERS * FE * FE) / 256) {
        const int i = d * 256 + t;
        const int l = i >> 12, rem = i & 4095;
        const int n = rem >> 6, k = rem & 63;
        Wt[(u32)(l * 4096 + n * 64 + k)] = f2bf(Wfij[(u32)(l * 4096 + k * 64 + n)]);
    }
    __syncthreads();

    if (t < 64) {
        float a0 = 0.f, a1 = 0.f;
        #pragma unroll 8
        for (int k = 0; k < FC; k += 2) {
            a0 = fmaf(row[k],     Wni[k * FE + t], a0);
            a1 = fmaf(row[k + 1], Wni[(k + 1) * FE + t], a1);
        }
        fni[d * FE + t] = f2bf(a0 + a1);
    } else if (t < 128) {
        const int f = t - 64;
        float a0 = 0.f, a1 = 0.f;
        #pragma unroll 8
        for (int k = 0; k < FC; k += 2) {
            a0 = fmaf(row[k],     Wnj[k * FE + f], a0);
            a1 = fmaf(row[k + 1], Wnj[(k + 1) * FE + f], a1);
        }
        fnj[d * FE + f] = f2bf(a0 + a1);
    } else {
        const int c = t - 128;
        float a0 = bias[c], a1 = 0.f;
        #pragma unroll 8
        for (int k = 0; k < FC; k += 2) {
            a0 = fmaf(row[k],     Wnode[k * FC + c], a0);
            a1 = fmaf(row[k + 1], Wnode[(k + 1) * FC + c], a1);
        }
        h[d * FC + c] = a0 + a1;
    }
}

// ---------------------------------------------------------------------------
// MFMA edge kernel, 2-TILE PIPELINED (r12, unchanged — 54.8 µs). Block =
// 4 waves x 2 tiles of 16 edges (grid E/128). All loads for both tiles
// issued up front (2x MLP). stage/fol LDS reused (wave-local; wave_barrier
// pins order). sidx/didx shuffles exec-full (r11 lesson: no shfl inside
// divergent branches).
// Fragment layouts (m89 family):
//   A: row=lane&15 (edge), k=(lane>>4)*8+j     B: col=lane&15 (n), same k
//   C: col=lane&15 (n),  row=(lane>>4)*4+reg   (edge)
// ---------------------------------------------------------------------------
template <bool FIRST, bool WRITE_EF>
__global__ void edge_mfma_kernel(
    u16* __restrict__ ef,                 // [E][64] bf16 (in/out)
    const float* __restrict__ x,          // [E][2]   (FIRST only)
    const float* __restrict__ Win,        // [2][64]  (FIRST only)
    const float* __restrict__ bin,        // [64]     (FIRST only)
    const u16* __restrict__ Wt,           // [64 n][64 k] bf16 (this layer)
    const u16* __restrict__ fni, const u16* __restrict__ fnj,
    const int* __restrict__ src, const int* __restrict__ dst,
    const float* __restrict__ attn,       // [64] fp32
    float* __restrict__ S)                // [N][N] fp32 (pre-zeroed)
{
    __shared__ __align__(16) u16 stage[4][16][72];               // fni+fnj sum
    __shared__ __align__(16) u16 fol[WRITE_EF ? 4 : 1][16][72];  // f_out rows

    const int lane = threadIdx.x & 63;
    const int wid  = threadIdx.x >> 6;
    const int l15  = lane & 15;
    const int grp  = lane >> 4;                       // 0..3
    const int block0 = blockIdx.x * 128;

    // --- issue ALL loads for both tiles up front (MLP) ---
    int tb[2], sv[2], dv[2];
    #pragma unroll
    for (int tt = 0; tt < 2; tt++) {
        tb[tt] = block0 + tt * 64 + wid * 16;
        sv[tt] = src[tb[tt] + l15];
        dv[tt] = dst[tb[tt] + l15];
    }

    u16x8 ga[2][2], gb[2][2];
    #pragma unroll
    for (int tt = 0; tt < 2; tt++) {
        #pragma unroll
        for (int it = 0; it < 2; it++) {
            const int row = it * 8 + (lane >> 3);     // 0..15
            const int c8 = (lane & 7) * 8;
            const int s = __shfl(sv[tt], row, 16);
            const int d = __shfl(dv[tt], row, 16);
            ga[tt][it] = *reinterpret_cast<const u16x8*>(fni + (u32)(s * FE + c8));
            gb[tt][it] = *reinterpret_cast<const u16x8*>(fnj + (u32)(d * FE + c8));
        }
    }

    bf16x8 afr[2][2];       // [tile][half]
    #pragma unroll
    for (int tt = 0; tt < 2; tt++) {
        if constexpr (FIRST) {
            const float2 xx = *reinterpret_cast<const float2*>(x + 2 * (u32)(tb[tt] + l15));
            #pragma unroll
            for (int half = 0; half < 2; half++) {
                const int c0 = half * 32 + grp * 8;
                const float4 wA0 = *reinterpret_cast<const float4*>(Win + c0);
                const float4 wA1 = *reinterpret_cast<const float4*>(Win + c0 + 4);
                const float4 wB0 = *reinterpret_cast<const float4*>(Win + FE + c0);
                const float4 wB1 = *reinterpret_cast<const float4*>(Win + FE + c0 + 4);
                const float4 b0  = *reinterpret_cast<const float4*>(bin + c0);
                const float4 b1  = *reinterpret_cast<const float4*>(bin + c0 + 4);
                u32x4 fr;
                fr[0] = cvt2bf(fmaf(xx.x, wA0.x, fmaf(xx.y, wB0.x, b0.x)),
                               fmaf(xx.x, wA0.y, fmaf(xx.y, wB0.y, b0.y)));
                fr[1] = cvt2bf(fmaf(xx.x, wA0.z, fmaf(xx.y, wB0.z, b0.z)),
                               fmaf(xx.x, wA0.w, fmaf(xx.y, wB0.w, b0.w)));
                fr[2] = cvt2bf(fmaf(xx.x, wA1.x, fmaf(xx.y, wB1.x, b1.x)),
                               fmaf(xx.x, wA1.y, fmaf(xx.y, wB1.y, b1.y)));
                fr[3] = cvt2bf(fmaf(xx.x, wA1.z, fmaf(xx.y, wB1.z, b1.z)),
                               fmaf(xx.x, wA1.w, fmaf(xx.y, wB1.w, b1.w)));
                afr[tt][half] = (bf16x8)fr;
            }
        } else {
            const u32 arow = (u32)(tb[tt] + l15) * FE;
            afr[tt][0] = *reinterpret_cast<const bf16x8*>(ef + arow + grp * 8);
            afr[tt][1] = *reinterpret_cast<const bf16x8*>(ef + arow + 32 + grp * 8);
        }
    }

    // --- B fragments: Wt[n][k]; n = nt*16+l15, k = ks*32+grp*8+j ---
    bf16x8 bfr[2][4];
    #pragma unroll
    for (int ks = 0; ks < 2; ks++)
        #pragma unroll
        for (int nt = 0; nt < 4; nt++)
            bfr[ks][nt] = *reinterpret_cast<const bf16x8*>(
                Wt + (u32)((nt * 16 + l15) * 64 + ks * 32 + grp * 8));

    float an[4];
    #pragma unroll
    for (int nt = 0; nt < 4; nt++) an[nt] = attn[nt * 16 + l15] * 1.44269504088896f;

    // --- process tiles sequentially, reusing stage/fol ---
    #pragma unroll
    for (int tt = 0; tt < 2; tt++) {
        #pragma unroll
        for (int it = 0; it < 2; it++) {
            const int row = it * 8 + (lane >> 3);
            const int c8 = (lane & 7) * 8;
            u32x4 s;
            #pragma unroll
            for (int j = 0; j < 4; j++) {
                s[j] = cvt2bf(bf2f(ga[tt][it][2*j])   + bf2f(gb[tt][it][2*j]),
                              bf2f(ga[tt][it][2*j+1]) + bf2f(gb[tt][it][2*j+1]));
            }
            *reinterpret_cast<u32x4*>(&stage[wid][row][c8]) = s;
        }

        f32x4 acc[4];
        #pragma unroll
        for (int nt = 0; nt < 4; nt++) {
            acc[nt] = (f32x4){0.f, 0.f, 0.f, 0.f};
            acc[nt] = __builtin_amdgcn_mfma_f32_16x16x32_bf16(afr[tt][0], bfr[0][nt], acc[nt], 0, 0, 0);
            acc[nt] = __builtin_amdgcn_mfma_f32_16x16x32_bf16(afr[tt][1], bfr[1][nt], acc[nt], 0, 0, 0);
        }

        __builtin_amdgcn_wave_barrier();   // stage writes <-> epilogue reads

        float logit[4] = {0.f, 0.f, 0.f, 0.f};
        #pragma unroll
        for (int nt = 0; nt < 4; nt++) {
            const int n = nt * 16 + l15;
            #pragma unroll
            for (int r = 0; r < 4; r++) {
                const int row = grp * 4 + r;          // edge slot in wave
                float v = acc[nt][r] + bf2f(stage[wid][row][n]);
                v = fmaxf(v, 0.2f * v);               // leaky_relu(0.2)
                logit[r] = fmaf(v, an[nt], logit[r]);
                if constexpr (WRITE_EF) fol[wid][row][n] = f2bf(v);
            }
        }

        // logit reduce (16 lanes/edge) + direct scatter into S
        #pragma unroll
        for (int r = 0; r < 4; r++) {
            float t = logit[r];
            t += __shfl_xor(t, 1, 16);
            t += __shfl_xor(t, 2, 16);
            t += __shfl_xor(t, 4, 16);
            t += __shfl_xor(t, 8, 16);
            const int sidx = __shfl(sv[tt], grp * 4 + r, 16);
            const int didx = __shfl(dv[tt], grp * 4 + r, 16);
            if (l15 == 0) {
                atomicAdd(S + (u32)(didx * N_NODES + sidx), exp2f(t));
            }
        }

        if constexpr (WRITE_EF) {
            __builtin_amdgcn_wave_barrier();   // fol writes <-> fol reads
            const u16x8 fo0 = *reinterpret_cast<const u16x8*>(&fol[wid][l15][grp * 8]);
            const u16x8 fo1 = *reinterpret_cast<const u16x8*>(&fol[wid][l15][32 + grp * 8]);
            u32x4 o0, o1;
            #pragma unroll
            for (int j = 0; j < 4; j++) {
                o0[j] = cvt2bf(bf2f((u16)afr[tt][0][2*j])   + bf2f(fo0[2*j]),
                               bf2f((u16)afr[tt][0][2*j+1]) + bf2f(fo0[2*j+1]));
                o1[j] = cvt2bf(bf2f((u16)afr[tt][1][2*j])   + bf2f(fo1[2*j]),
                               bf2f((u16)afr[tt][1][2*j+1]) + bf2f(fo1[2*j+1]));
            }
            u16* gp = ef + (u32)(tb[tt] + l15) * FE;
            *reinterpret_cast<u32x4*>(gp + grp * 8) = o0;
            *reinterpret_cast<u32x4*>(gp + 32 + grp * 8) = o1;
        }

        __builtin_amdgcn_wave_barrier();   // protect stage/fol reuse by tile 1
    }
}

// ---------------------------------------------------------------------------
// spmm (r13 = r10 design restored; r11's 4-row variant dropped occupancy to
// 1 block/CU and ran 53 µs vs ~16 — occupancy beats traffic-saving for
// L2-resident h). 1024 blocks, 1 dst row each: nout = nin + (S@h)/rowsum(S).
// For !LAST: re-zero S row, write nodeA, next-layer projections (h dbuf).
// ---------------------------------------------------------------------------
template <bool LAST>
__global__ __launch_bounds__(256) void spmm_kernel(
    float* __restrict__ S, const float* __restrict__ h,
    const float* __restrict__ nin, float* __restrict__ nout,
    const float* __restrict__ Wni, const float* __restrict__ Wnj,
    const float* __restrict__ Wnode, const float* __restrict__ bias,
    u16* __restrict__ fni, u16* __restrict__ fnj, float* __restrict__ hnext)
{
    __shared__ float red[256];
    __shared__ float rs[2];
    __shared__ float row[FC];
    const int d = blockIdx.x;
    const int t = threadIdx.x;
    const int c = t & 127;
    const int half = t >> 7;
    const float* Srow = S + (u32)d * N_NODES + half * 512;
    const float* hp = h + (u32)(half * 512 * FC);
    float a0 = 0.f, a1 = 0.f, a2 = 0.f, a3 = 0.f;
    float r0 = 0.f, r1 = 0.f, r2 = 0.f, r3 = 0.f;
    #pragma unroll 4
    for (int n = 0; n < 512; n += 4) {
        const float s0 = Srow[n], s1 = Srow[n+1], s2 = Srow[n+2], s3 = Srow[n+3];
        r0 += s0; r1 += s1; r2 += s2; r3 += s3;
        a0 = fmaf(s0, hp[n * FC + c], a0);
        a1 = fmaf(s1, hp[(n+1) * FC + c], a1);
        a2 = fmaf(s2, hp[(n+2) * FC + c], a2);
        a3 = fmaf(s3, hp[(n+3) * FC + c], a3);
    }
    red[t] = (a0 + a1) + (a2 + a3);
    if (c == 0) rs[half] = (r0 + r1) + (r2 + r3);
    __syncthreads();

    if constexpr (!LAST) {   // re-zero S row for next layer (reads done)
        reinterpret_cast<float4*>(S + (u32)d * N_NODES)[t] = make_float4(0.f, 0.f, 0.f, 0.f);
    }
    if (half == 0) {
        const float v = nin[d * FC + c] + (red[c] + red[128 + c]) / (rs[0] + rs[1]);
        nout[d * FC + c] = v;
        if constexpr (!LAST) row[c] = v;
    }

    if constexpr (!LAST) {
        __syncthreads();
        if (t < 64) {
            float b0 = 0.f, b1 = 0.f;
            #pragma unroll 8
            for (int k = 0; k < FC; k += 2) {
                b0 = fmaf(row[k],     Wni[k * FE + t], b0);
                b1 = fmaf(row[k + 1], Wni[(k + 1) * FE + t], b1);
            }
            fni[d * FE + t] = f2bf(b0 + b1);
        } else if (t < 128) {
            const int f = t - 64;
            float b0 = 0.f, b1 = 0.f;
            #pragma unroll 8
            for (int k = 0; k < FC; k += 2) {
                b0 = fmaf(row[k],     Wnj[k * FE + f], b0);
                b1 = fmaf(row[k + 1], Wnj[(k + 1) * FE + f], b1);
            }
            fnj[d * FE + f] = f2bf(b0 + b1);
        } else {
            const int cc = t - 128;
            float b0 = bias[cc], b1 = 0.f;
            #pragma unroll 8
            for (int k = 0; k < FC; k += 2) {
                b0 = fmaf(row[k],     Wnode[k * FC + cc], b0);
                b1 = fmaf(row[k + 1], Wnode[(k + 1) * FC + cc], b1);
            }
            hnext[d * FC + cc] = b0 + b1;
        }
    }
}

// ---------------------------------------------------------------------------
extern "C" void kernel_launch(void* const* d_in, const int* in_sizes, int n_in,
                              void* d_out, int out_size, void* d_ws, size_t ws_size,
                              hipStream_t stream)
{
    const float* node_feature = (const float*)d_in[0];
    const float* edge_feature = (const float*)d_in[1];
    const int*   src          = (const int*)d_in[2];
    const int*   dst          = (const int*)d_in[3];
    const float* W_in         = (const float*)d_in[4];
    const float* b_in         = (const float*)d_in[5];
    const float* W_ni         = (const float*)d_in[6];
    const float* W_nj         = (const float*)d_in[7];
    const float* W_fij        = (const float*)d_in[8];
    const float* W_node       = (const float*)d_in[9];
    const float* attn         = (const float*)d_in[10];
    const float* bias_node    = (const float*)d_in[11];
    float* out = (float*)d_out;

    char* ws = (char*)d_ws;
    size_t off = 0;
    auto alloc = [&](size_t bytes) -> void* {
        void* pp = ws + off;
        off += (bytes + 255) & ~(size_t)255;
        return pp;
    };
    u16*   ef    = (u16*)alloc((size_t)E_EDGES * FE * sizeof(u16));       // 67 MB
    u16*   fni   = (u16*)alloc(N_NODES * FE * sizeof(u16));
    u16*   fnj   = (u16*)alloc(N_NODES * FE * sizeof(u16));
    float* h0    = (float*)alloc(N_NODES * FC * sizeof(float));
    float* h1    = (float*)alloc(N_NODES * FC * sizeof(float));
    float* S     = (float*)alloc((size_t)N_NODES * N_NODES * sizeof(float)); // 4 MB
    float* nodeA = (float*)alloc(N_NODES * FC * sizeof(float));
    u16*   Wt    = (u16*)alloc((size_t)NLAYERS * FE * FE * sizeof(u16));  // 24 KB
    float* hbuf[2] = {h0, h1};

    setup_kernel<<<N_NODES, 256, 0, stream>>>(
        node_feature, W_fij, Wt, W_ni, W_nj, W_node, bias_node,
        fni, fnj, h0, S, nodeA);

    for (int l = 0; l < NLAYERS; l++) {
        float* hl = hbuf[l & 1];
        float* hn = hbuf[(l + 1) & 1];

        if (l == 0) {
            edge_mfma_kernel<true, true><<<E_EDGES / 128, 256, 0, stream>>>(
                ef, edge_feature, W_in, b_in, Wt + (size_t)l * FE * FE,
                fni, fnj, src, dst, attn + (size_t)l * FE, S);
        } else if (l == NLAYERS - 1) {
            edge_mfma_kernel<false, false><<<E_EDGES / 128, 256, 0, stream>>>(
                ef, nullptr, nullptr, nullptr, Wt + (size_t)l * FE * FE,
                fni, fnj, src, dst, attn + (size_t)l * FE, S);
        } else {
            edge_mfma_kernel<false, true><<<E_EDGES / 128, 256, 0, stream>>>(
                ef, nullptr, nullptr, nullptr, Wt + (size_t)l * FE * FE,
                fni, fnj, src, dst, attn + (size_t)l * FE, S);
        }

        if (l == NLAYERS - 1) {
            spmm_kernel<true><<<N_NODES, 256, 0, stream>>>(
                S, hl, nodeA, out,
                nullptr, nullptr, nullptr, nullptr, nullptr, nullptr, nullptr);
        } else {
            const int ln = l + 1;
            spmm_kernel<false><<<N_NODES, 256, 0, stream>>>(
                S, hl, nodeA, nodeA,
                W_ni + (size_t)ln * FC * FE, W_nj + (size_t)ln * FC * FE,
                W_node + (size_t)ln * FC * FC, bias_node + (size_t)ln * FC,
                fni, fnj, hn);
        }
    }
}